// Round 3
// baseline (181.847 us; speedup 1.0000x reference)
//
#include <hip/hip_runtime.h>
#include <hip/hip_bf16.h>

#define NB   64
#define SL   1024
#define EMB  128
#define NSK  1000
#define TI   64
#define SB   136   // LDS row stride in bf16 elems: 272B -> aligned b128, balanced banks
#define NS   2     // split over j-128-tile parity

// bf16 table layout in ws (elements):
#define AI_OFF 0
#define BI_OFF 256000
#define AS_OFF 512000
#define BS_OFF 640000
#define TB_ELEMS 768000
#define ACC_BYTE_OFF (TB_ELEMS * 2)   // 1,536,000 B (16B aligned)
// acc: [16][NB][SL] floats = 4 MB

using short8  = __attribute__((ext_vector_type(8))) short;
using floatx4 = __attribute__((ext_vector_type(4))) float;

// exp(-b*log5(dt)) = exp2(-b*log2(dt)/ln(5)); 1/ln(5):
#define INV_LN5 0.6213349345596119f

__device__ inline unsigned cvt2(float x, float y) {
    float2 f; f.x = x; f.y = y;
    __hip_bfloat162 h = __float22bfloat162_rn(f);
    unsigned u; __builtin_memcpy(&u, &h, sizeof(u));
    return u;
}

// ---- one-time fp32 -> bf16 table conversion (8 elems/thread) ----
extern "C" __global__ __launch_bounds__(256)
void cvt_tables(const float* __restrict__ ai, const float* __restrict__ bi,
                const float* __restrict__ as, const float* __restrict__ bs,
                unsigned short* __restrict__ dst)
{
    const int t = blockIdx.x * 256 + threadIdx.x;   // 96000 threads
    const long e = (long)t * 8;
    const float* src;
    if      (e < 256000) src = ai + e;
    else if (e < 512000) src = bi + (e - 256000);
    else if (e < 640000) src = as + (e - 512000);
    else                 src = bs + (e - 640000);
    float4 f0 = *(const float4*)src;
    float4 f1 = *(const float4*)(src + 4);
    uint4 pk;
    pk.x = cvt2(f0.x, f0.y); pk.y = cvt2(f0.z, f0.w);
    pk.z = cvt2(f1.x, f1.y); pk.w = cvt2(f1.z, f1.w);
    *(uint4*)(dst + e) = pk;
}

// exact fp32 recompute for duplicate-timestamp pairs (dt==0, i<j):
// contribution = alpha_dot * exp(beta' * 14.306765580733931)   [= -log(1e-10)/log(5)]
__device__ __noinline__ float fixup_pair(const float* __restrict__ air,
                                         const float* __restrict__ bir,
                                         const float* __restrict__ asr,
                                         const float* __restrict__ bsr) {
    float da = 0.f, db = 0.f;
    for (int k = 0; k < EMB; ++k) {
        da += air[k] * asr[k];
        db += bir[k] * bsr[k];
    }
    float beta = fminf(fmaxf(db + 1.f, 0.f), 10.f);
    return da * __expf(beta * 14.30676558073393f);
}

extern "C" __global__ __launch_bounds__(256)
void hawkes_main(const int*   __restrict__ inp,     // (B,4,L) int32
                 const float* __restrict__ ainter,  // fp32, fixup only
                 const float* __restrict__ askill,  // fp32, fixup only
                 const float* __restrict__ bint,    // fp32, fixup only
                 const float* __restrict__ bsk,     // fp32, fixup only
                 const unsigned short* __restrict__ tb,  // bf16 tables
                 float*       __restrict__ acc)     // [16][NB][SL] partials
{
    __shared__ unsigned short lA[2][TI][SB];   // [0]=alpha_inter rows, [1]=beta_inter rows

    const int bid  = blockIdx.x;
    const int b    = bid & (NB - 1);
    const int r    = bid >> 6;        // 0..31
    const int it   = r >> 1;          // 0..15  (ascending => most work first)
    const int s    = r & 1;           // j-tile parity split
    const int tid  = threadIdx.x;
    const int w    = tid >> 6;        // wave 0..3
    const int l    = tid & 63;
    const int quad = l >> 4;
    const int col  = l & 15;

    const int* __restrict__ binp = inp + b * 4 * SL;
    const int itb = it * TI;

    // ---- stage A tile once (gathered bf16 copy) ----
    {
        const int srow  = tid >> 2;
        const int sq    = tid & 3;
        const int irow  = itb + srow;
        const int ski   = binp[irow];
        const int li    = binp[2 * SL + irow];
        const long intr = ski + (long)li * NSK;
        const unsigned short* sA  = tb + AI_OFF + intr * EMB + sq * 32;
        const unsigned short* sBm = tb + BI_OFF + intr * EMB + sq * 32;
        uint4 a0 = *(const uint4*)(sA);
        uint4 a1 = *(const uint4*)(sA + 8);
        uint4 a2 = *(const uint4*)(sA + 16);
        uint4 a3 = *(const uint4*)(sA + 24);
        uint4 b0 = *(const uint4*)(sBm);
        uint4 b1 = *(const uint4*)(sBm + 8);
        uint4 b2 = *(const uint4*)(sBm + 16);
        uint4 b3 = *(const uint4*)(sBm + 24);
        unsigned short* dA = &lA[0][srow][sq * 32];
        unsigned short* dB = &lA[1][srow][sq * 32];
        *(uint4*)(dA)      = a0; *(uint4*)(dA + 8)  = a1;
        *(uint4*)(dA + 16) = a2; *(uint4*)(dA + 24) = a3;
        *(uint4*)(dB)      = b0; *(uint4*)(dB + 8)  = b1;
        *(uint4*)(dB + 16) = b2; *(uint4*)(dB + 24) = b3;
    }

    // hoist times of this block's i-rows (C row = quad*4+reg)
    int4 t4s[4];
#pragma unroll
    for (int isub = 0; isub < 4; ++isub)
        t4s[isub] = *(const int4*)(binp + 3 * SL + itb + isub * 16 + quad * 4);

    __syncthreads();   // the only barrier

    const int jt_min = it >> 1;
    for (int jt = jt_min; jt < 8; ++jt) {
        if ((jt & 1) != s) continue;
        const int jbase = jt * 128 + w * 32;
        const int j0 = jbase + col;
        const int j1 = jbase + 16 + col;
        const int sk0 = binp[j0],        sk1 = binp[j1];
        const int tj0 = binp[3*SL + j0], tj1 = binp[3*SL + j1];

        // gather B fragments for both j-halves, both matrices
        short8 f00[4], f01[4], f10[4], f11[4];   // [half][mat][ks]
        {
            const unsigned short* p00 = tb + AS_OFF + (long)sk0 * EMB + quad * 8;
            const unsigned short* p01 = tb + BS_OFF + (long)sk0 * EMB + quad * 8;
            const unsigned short* p10 = tb + AS_OFF + (long)sk1 * EMB + quad * 8;
            const unsigned short* p11 = tb + BS_OFF + (long)sk1 * EMB + quad * 8;
#pragma unroll
            for (int ks = 0; ks < 4; ++ks) {
                f00[ks] = *(const short8*)(p00 + ks * 32);
                f01[ks] = *(const short8*)(p01 + ks * 32);
                f10[ks] = *(const short8*)(p10 + ks * 32);
                f11[ks] = *(const short8*)(p11 + ks * 32);
            }
        }

        float sum0 = 0.f, sum1 = 0.f;
#pragma unroll
        for (int isub = 0; isub < 4; ++isub) {
            floatx4 aa0 = {0.f,0.f,0.f,0.f}, aa1 = {0.f,0.f,0.f,0.f};
            floatx4 bb0 = {0.f,0.f,0.f,0.f}, bb1 = {0.f,0.f,0.f,0.f};
#pragma unroll
            for (int ks = 0; ks < 4; ++ks) {
                const int k0 = ks * 32 + quad * 8;
                short8 av = *(const short8*)&lA[0][isub * 16 + col][k0];
                short8 bv = *(const short8*)&lA[1][isub * 16 + col][k0];
                aa0 = __builtin_amdgcn_mfma_f32_16x16x32_bf16(av, f00[ks], aa0, 0, 0, 0);
                aa1 = __builtin_amdgcn_mfma_f32_16x16x32_bf16(av, f10[ks], aa1, 0, 0, 0);
                bb0 = __builtin_amdgcn_mfma_f32_16x16x32_bf16(bv, f01[ks], bb0, 0, 0, 0);
                bb1 = __builtin_amdgcn_mfma_f32_16x16x32_bf16(bv, f11[ks], bb1, 0, 0, 0);
            }
            const int ibase = itb + isub * 16 + quad * 4;
            const int4 t4 = t4s[isub];
#pragma unroll
            for (int rr = 0; rr < 4; ++rr) {
                const int iidx = ibase + rr;
                const int ti = (rr == 0) ? t4.x : (rr == 1) ? t4.y : (rr == 2) ? t4.z : t4.w;
                if (iidx < j0) {
                    const int dt = tj0 - ti;
                    if (dt != 0) {
                        float beta = fminf(fmaxf(bb0[rr] + 1.f, 0.f), 10.f);
                        sum0 += aa0[rr] * exp2f(-beta * (__log2f((float)dt) * INV_LN5));
                    } else {
                        const int ski = binp[iidx], li = binp[2*SL + iidx];
                        const long intr = ski + (long)li * NSK;
                        sum0 += fixup_pair(ainter + intr * EMB, bint + intr * EMB,
                                           askill + (long)sk0 * EMB, bsk + (long)sk0 * EMB);
                    }
                }
                if (iidx < j1) {
                    const int dt = tj1 - ti;
                    if (dt != 0) {
                        float beta = fminf(fmaxf(bb1[rr] + 1.f, 0.f), 10.f);
                        sum1 += aa1[rr] * exp2f(-beta * (__log2f((float)dt) * INV_LN5));
                    } else {
                        const int ski = binp[iidx], li = binp[2*SL + iidx];
                        const long intr = ski + (long)li * NSK;
                        sum1 += fixup_pair(ainter + intr * EMB, bint + intr * EMB,
                                           askill + (long)sk1 * EMB, bsk + (long)sk1 * EMB);
                    }
                }
            }
        }

        // reduce quads (same col => same j), write partials (write-once, no atomics)
        sum0 += __shfl_xor(sum0, 16, 64); sum0 += __shfl_xor(sum0, 32, 64);
        sum1 += __shfl_xor(sum1, 16, 64); sum1 += __shfl_xor(sum1, 32, 64);
        if (quad == 0) {
            float* as_ = acc + (((long)it * NB + b) << 10);
            as_[j0] = sum0;
            as_[j1] = sum1;
        }
    }
}

extern "C" __global__ __launch_bounds__(256)
void hawkes_finalize(const int* __restrict__ inp, const float* __restrict__ pbase,
                     const float* __restrict__ sbase, const float* __restrict__ acc,
                     float* __restrict__ out)
{
    const int t = blockIdx.x * 256 + threadIdx.x;   // 65536
    const int b = t >> 10, j = t & (SL - 1);
    const int* binp = inp + b * 4 * SL;
    const int itmax = min(15, 2 * (j >> 7) + 1);    // exactly the written slices
    float sum = 0.f;
    for (int it = 0; it <= itmax; ++it)
        sum += acc[(((long)it * NB + b) << 10) + j];
    const float x = pbase[binp[SL + j]] + sbase[binp[j]] + sum;
    out[t] = 1.f / (1.f + __expf(-x));
}

extern "C" void kernel_launch(void* const* d_in, const int* in_sizes, int n_in,
                              void* d_out, int out_size, void* d_ws, size_t ws_size,
                              hipStream_t stream) {
    const int*   inp = (const int*)d_in[0];
    const float* pb  = (const float*)d_in[1];
    const float* sb  = (const float*)d_in[2];
    const float* ai  = (const float*)d_in[3];
    const float* as  = (const float*)d_in[4];
    const float* bi  = (const float*)d_in[5];
    const float* bs  = (const float*)d_in[6];

    unsigned short* tb  = (unsigned short*)d_ws;
    float*          acc = (float*)((char*)d_ws + ACC_BYTE_OFF);

    cvt_tables<<<dim3(96000 / 256), dim3(256), 0, stream>>>(ai, bi, as, bs, tb);
    hawkes_main<<<dim3(NB * 16 * NS), dim3(256), 0, stream>>>(
        inp, ai, as, bi, bs, tb, acc);
    hawkes_finalize<<<dim3(NB * SL / 256), dim3(256), 0, stream>>>(
        inp, pb, sb, acc, (float*)d_out);
}

// Round 4
// 115.062 us; speedup vs baseline: 1.5804x; 1.5804x over previous
//
#include <hip/hip_runtime.h>
#include <hip/hip_bf16.h>

#define NB   64
#define SL   1024
#define EMB  128
#define NSK  1000
#define TI   64
#define SB   136   // LDS row stride in bf16 elems: 272B -> b128-aligned, balanced banks
#define NS   2     // split of i-tiles per j-tile

// bf16 table layout in ws (elements):
#define AI_OFF 0
#define BI_OFF 256000
#define AS_OFF 512000
#define BS_OFF 640000
#define TB_ELEMS 768000
#define ACC_BYTE_OFF (TB_ELEMS * 2)   // acc: [NS][NB][SL] float = 512 KB

using short8  = __attribute__((ext_vector_type(8))) short;
using floatx4 = __attribute__((ext_vector_type(4))) float;

// exp(-b*log5(dt)) = exp2(-b*log2(dt)/ln... ); 1/ln(5) in log2 base: log5(x)=log2(x)*INV_LOG2_5
#define INV_LOG2_5 0.43067655807339306f
// NOTE: log5(dt) = ln(dt)/ln(5) = log2(dt)*ln(2)/ln(5) = log2(dt)*0.43067655807339306

__device__ inline unsigned cvt2(float x, float y) {
    float2 f; f.x = x; f.y = y;
    __hip_bfloat162 h = __float22bfloat162_rn(f);
    unsigned u; __builtin_memcpy(&u, &h, sizeof(u));
    return u;
}

// ---- one-time fp32 -> bf16 table conversion (8 elems/thread) ----
extern "C" __global__ __launch_bounds__(256)
void cvt_tables(const float* __restrict__ ai, const float* __restrict__ bi,
                const float* __restrict__ as, const float* __restrict__ bs,
                unsigned short* __restrict__ dst)
{
    const int t = blockIdx.x * 256 + threadIdx.x;   // 96000 threads
    const long e = (long)t * 8;
    const float* src;
    if      (e < 256000) src = ai + e;
    else if (e < 512000) src = bi + (e - 256000);
    else if (e < 640000) src = as + (e - 512000);
    else                 src = bs + (e - 640000);
    float4 f0 = *(const float4*)src;
    float4 f1 = *(const float4*)(src + 4);
    uint4 pk;
    pk.x = cvt2(f0.x, f0.y); pk.y = cvt2(f0.z, f0.w);
    pk.z = cvt2(f1.x, f1.y); pk.w = cvt2(f1.z, f1.w);
    *(uint4*)(dst + e) = pk;
}

// exact fp32 path for duplicate-timestamp pairs (dt==0, i<j):
// contribution = alpha_dot * exp(beta' * 14.306765580733931)   [= -log(1e-10)/log(5)]
__device__ float fixup_pair(const float* __restrict__ air,
                            const float* __restrict__ bir,
                            const float* __restrict__ asr,
                            const float* __restrict__ bsr) {
    float da = 0.f, db = 0.f;
    for (int k = 0; k < EMB; ++k) {
        da += air[k] * asr[k];
        db += bir[k] * bsr[k];
    }
    float beta = fminf(fmaxf(db + 1.f, 0.f), 10.f);
    return da * __expf(beta * 14.30676558073393f);
}

extern "C" __global__ __launch_bounds__(256, 4)
void hawkes_main(const int*   __restrict__ inp,     // (B,4,L) int32
                 const unsigned short* __restrict__ tb,  // bf16 tables
                 float*       __restrict__ acc)     // [NS][NB][SL] partials
{
    __shared__ unsigned short lA[2][TI][SB];   // [0]=alpha_inter rows, [1]=beta_inter rows

    const int bid  = blockIdx.x;
    const int b    = bid & (NB - 1);
    const int r    = bid >> 6;                 // 0..31
    const int jt   = 15 - (r >> 1);            // heavy tiles dispatch first
    const int s    = r & 1;
    const int tid  = threadIdx.x;
    const int w    = tid >> 6;                 // wave -> 16-j strip
    const int l    = tid & 63;
    const int quad = l >> 4;
    const int col  = l & 15;

    const int* __restrict__ binp = inp + b * 4 * SL;

    const int jlane = jt * TI + w * 16 + col;
    const int sk_j  = binp[jlane];
    const int tj    = binp[3 * SL + jlane];

    // ---- B fragments (skill rows of this lane's j), fixed for whole block ----
    const unsigned short* asr16 = tb + AS_OFF + (long)sk_j * EMB + quad * 8;
    const unsigned short* bsr16 = tb + BS_OFF + (long)sk_j * EMB + quad * 8;
    short8 bfa[4], bfb[4];
#pragma unroll
    for (int ks = 0; ks < 4; ++ks) {
        bfa[ks] = *(const short8*)(asr16 + ks * 32);
        bfb[ks] = *(const short8*)(bsr16 + ks * 32);
    }

    const int srow = tid >> 2;                 // staging: row
    const int sq   = tid & 3;                  // staging: 32-elem quarter
    unsigned short* dA = &lA[0][srow][sq * 32];
    unsigned short* dB = &lA[1][srow][sq * 32];

    float sum = 0.f;

    if (s <= jt) {
        // ---- prefetch first tile into registers ----
        uint4 pa0, pa1, pa2, pa3, pb0, pb1, pb2, pb3;
        {
            const int irow  = s * TI + srow;
            const int ski   = binp[irow];
            const int li    = binp[2 * SL + irow];
            const long intr = ski + (long)li * NSK;
            const unsigned short* sA  = tb + AI_OFF + intr * EMB + sq * 32;
            const unsigned short* sBm = tb + BI_OFF + intr * EMB + sq * 32;
            pa0 = *(const uint4*)(sA);      pa1 = *(const uint4*)(sA + 8);
            pa2 = *(const uint4*)(sA + 16); pa3 = *(const uint4*)(sA + 24);
            pb0 = *(const uint4*)(sBm);     pb1 = *(const uint4*)(sBm + 8);
            pb2 = *(const uint4*)(sBm + 16);pb3 = *(const uint4*)(sBm + 24);
        }

        for (int it = s; it <= jt; it += NS) {
            __syncthreads();   // previous compute done -> safe to overwrite LDS
            *(uint4*)(dA)      = pa0; *(uint4*)(dA + 8)  = pa1;
            *(uint4*)(dA + 16) = pa2; *(uint4*)(dA + 24) = pa3;
            *(uint4*)(dB)      = pb0; *(uint4*)(dB + 8)  = pb1;
            *(uint4*)(dB + 16) = pb2; *(uint4*)(dB + 24) = pb3;

            // issue next tile's loads now; latency hides under compute
            if (it + NS <= jt) {
                const int irow  = (it + NS) * TI + srow;
                const int ski   = binp[irow];
                const int li    = binp[2 * SL + irow];
                const long intr = ski + (long)li * NSK;
                const unsigned short* sA  = tb + AI_OFF + intr * EMB + sq * 32;
                const unsigned short* sBm = tb + BI_OFF + intr * EMB + sq * 32;
                pa0 = *(const uint4*)(sA);      pa1 = *(const uint4*)(sA + 8);
                pa2 = *(const uint4*)(sA + 16); pa3 = *(const uint4*)(sA + 24);
                pb0 = *(const uint4*)(sBm);     pb1 = *(const uint4*)(sBm + 8);
                pb2 = *(const uint4*)(sBm + 16);pb3 = *(const uint4*)(sBm + 24);
            }
            __syncthreads();   // publish LDS tile

            const int itb = it * TI;
#pragma unroll
            for (int isub = 0; isub < 4; ++isub) {
                floatx4 aa = {0.f, 0.f, 0.f, 0.f};
                floatx4 bb = {0.f, 0.f, 0.f, 0.f};
#pragma unroll
                for (int ks = 0; ks < 4; ++ks) {
                    const int k0 = ks * 32 + quad * 8;
                    short8 av = *(const short8*)&lA[0][isub * 16 + col][k0];
                    short8 bv = *(const short8*)&lA[1][isub * 16 + col][k0];
                    aa = __builtin_amdgcn_mfma_f32_16x16x32_bf16(av, bfa[ks], aa, 0, 0, 0);
                    bb = __builtin_amdgcn_mfma_f32_16x16x32_bf16(bv, bfb[ks], bb, 0, 0, 0);
                }
                const int ibase = itb + isub * 16 + quad * 4;   // C row = quad*4+reg
                const int4 t4 = *(const int4*)(binp + 3 * SL + ibase);
#pragma unroll
                for (int rr = 0; rr < 4; ++rr) {
                    const int ti = (rr == 0) ? t4.x : (rr == 1) ? t4.y : (rr == 2) ? t4.z : t4.w;
                    const int dt = tj - ti;
                    // sorted times => (i<j && dt>0) <=> dt>0 ; dt==0 (dup) handled in finalize
                    float lc  = __log2f((float)dt);                       // junk if dt<=0, discarded
                    float nb  = fminf(fmaxf(bb[rr] + 1.f, 0.f), 10.f) * (-INV_LOG2_5);
                    float arg = (dt > 0) ? nb * lc : -__builtin_inff();
                    sum += aa[rr] * exp2f(arg);
                }
            }
        }
    }

    // reduce the 4 quads holding the same j
    sum += __shfl_xor(sum, 16, 64);
    sum += __shfl_xor(sum, 32, 64);

    if (quad == 0) {
        acc[(((long)s * NB + b) << 10) + jlane] = sum;   // write-once, no init needed
    }
}

extern "C" __global__ __launch_bounds__(256)
void hawkes_finalize(const int* __restrict__ inp, const float* __restrict__ pbase,
                     const float* __restrict__ sbase,
                     const float* __restrict__ ai, const float* __restrict__ as,
                     const float* __restrict__ bi, const float* __restrict__ bs,
                     const float* __restrict__ acc, float* __restrict__ out)
{
    const int t = blockIdx.x * 256 + threadIdx.x;   // 65536
    const int b = t >> 10, j = t & (SL - 1);
    const int* binp = inp + b * 4 * SL;
    const int tj   = binp[3 * SL + j];
    const int sk_j = binp[j];

    // exact fp32 correction for duplicate-timestamp pairs (adjacent in sorted order)
    float corr = 0.f;
    for (int i = j - 1; i >= 0 && binp[3 * SL + i] == tj; --i) {
        const int ski = binp[i], li = binp[2 * SL + i];
        const long intr = ski + (long)li * NSK;
        corr += fixup_pair(ai + intr * EMB, bi + intr * EMB,
                           as + (long)sk_j * EMB, bs + (long)sk_j * EMB);
    }

    float sum = acc[t] + acc[NB * SL + t] + corr;
    const float x = pbase[binp[SL + j]] + sbase[sk_j] + sum;
    out[t] = 1.f / (1.f + __expf(-x));
}

extern "C" void kernel_launch(void* const* d_in, const int* in_sizes, int n_in,
                              void* d_out, int out_size, void* d_ws, size_t ws_size,
                              hipStream_t stream) {
    const int*   inp = (const int*)d_in[0];
    const float* pb  = (const float*)d_in[1];
    const float* sb  = (const float*)d_in[2];
    const float* ai  = (const float*)d_in[3];
    const float* as  = (const float*)d_in[4];
    const float* bi  = (const float*)d_in[5];
    const float* bs  = (const float*)d_in[6];

    unsigned short* tb  = (unsigned short*)d_ws;
    float*          acc = (float*)((char*)d_ws + ACC_BYTE_OFF);

    cvt_tables<<<dim3(96000 / 256), dim3(256), 0, stream>>>(ai, bi, as, bs, tb);
    hawkes_main<<<dim3(NB * 16 * NS), dim3(256), 0, stream>>>(inp, tb, acc);
    hawkes_finalize<<<dim3(NB * SL / 256), dim3(256), 0, stream>>>(
        inp, pb, sb, ai, as, bi, bs, acc, (float*)d_out);
}